// Round 19
// baseline (12674.752 us; speedup 1.0000x reference)
//
#include <hip/hip_runtime.h>

#define NPTS 32768
#define NSUB 8192
#define INC 256
#define OUTC 128
#define KNN 8
#define TOPL 10
#define NT_TOL 1.0e-6f
#define BN_EPS 1e-5f

__device__ __forceinline__ float silu_f(float v) {
    return v / (1.0f + __expf(-v));
}

// ---------------- K0: pack pos_sub -> float4(x,y,z,|q|^2) in workspace -------
__global__ __launch_bounds__(256) void k0_pack(
    const float* __restrict__ pos_sub, float4* __restrict__ ps4) {
  int s = blockIdx.x * 256 + threadIdx.x;
  if (s < NSUB) {
    float qx = pos_sub[s * 3 + 0];
    float qy = pos_sub[s * 3 + 1];
    float qz = pos_sub[s * 3 + 2];
    float nrm = __fadd_rn(__fadd_rn(__fmul_rn(qx, qx), __fmul_rn(qy, qy)),
                          __fmul_rn(qz, qz));
    ps4[s] = make_float4(qx, qy, qz, nrm);
  }
}

// ---------------- K1: asrc = x_sub @ Wsrc, vlin = x_sub @ Wlin ----------------
__global__ __launch_bounds__(256) void k1_proj_sub(
    const float* __restrict__ x_sub, const float* __restrict__ Wsrc,
    const float* __restrict__ Wlin, float* __restrict__ asrc,
    float* __restrict__ vlin) {
  __shared__ __align__(16) float xs[32 * INC];
  const int tid = threadIdx.x;
  const int r0 = blockIdx.x * 32;
  {
    const float4* src = (const float4*)(x_sub + (size_t)r0 * INC);
    float4* dst = (float4*)xs;
    #pragma unroll
    for (int i = 0; i < 8; ++i) dst[tid + 256 * i] = src[tid + 256 * i];
  }
  __syncthreads();
  const int cq = tid & 31;
  const int rg = tid >> 5;
  float4 acc_s[4], acc_l[4];
  #pragma unroll
  for (int i = 0; i < 4; ++i) {
    acc_s[i] = make_float4(0.f, 0.f, 0.f, 0.f);
    acc_l[i] = make_float4(0.f, 0.f, 0.f, 0.f);
  }
  const float4* Ws4 = (const float4*)Wsrc;
  const float4* Wl4 = (const float4*)Wlin;
  #pragma unroll 2
  for (int d = 0; d < INC; ++d) {
    float4 ws = Ws4[d * 32 + cq];
    float4 wl = Wl4[d * 32 + cq];
    #pragma unroll
    for (int i = 0; i < 4; ++i) {
      float xv = xs[(rg * 4 + i) * INC + d];
      acc_s[i].x += xv * ws.x; acc_s[i].y += xv * ws.y;
      acc_s[i].z += xv * ws.z; acc_s[i].w += xv * ws.w;
      acc_l[i].x += xv * wl.x; acc_l[i].y += xv * wl.y;
      acc_l[i].z += xv * wl.z; acc_l[i].w += xv * wl.w;
    }
  }
  #pragma unroll
  for (int i = 0; i < 4; ++i) {
    int r = r0 + rg * 4 + i;
    ((float4*)(asrc + (size_t)r * OUTC))[cq] = acc_s[i];
    ((float4*)(vlin + (size_t)r * OUTC))[cq] = acc_l[i];
  }
}

// ---------------- K2: adst = x @ Wdst ; d_out = silu(BN(x @ Wm + bm)) --------
__global__ __launch_bounds__(256) void k2_proj_x(
    const float* __restrict__ x, const float* __restrict__ Wdst,
    const float* __restrict__ Wm, const float* __restrict__ bm,
    const float* __restrict__ gamma, const float* __restrict__ beta,
    const float* __restrict__ rmean, const float* __restrict__ rvar,
    float* __restrict__ adst, float* __restrict__ out) {
  __shared__ __align__(16) float xt[32 * OUTC];
  const int tid = threadIdx.x;
  const int r0 = blockIdx.x * 32;
  {
    const float4* src = (const float4*)(x + (size_t)r0 * OUTC);
    float4* dst = (float4*)xt;
    #pragma unroll
    for (int i = 0; i < 4; ++i) dst[tid + 256 * i] = src[tid + 256 * i];
  }
  __syncthreads();
  const int cq = tid & 31;
  const int rg = tid >> 5;
  float4 ad[4], am[4];
  #pragma unroll
  for (int i = 0; i < 4; ++i) {
    ad[i] = make_float4(0.f, 0.f, 0.f, 0.f);
    am[i] = make_float4(0.f, 0.f, 0.f, 0.f);
  }
  const float4* Wd4 = (const float4*)Wdst;
  const float4* Wm4 = (const float4*)Wm;
  #pragma unroll 2
  for (int d = 0; d < OUTC; ++d) {
    float4 wd = Wd4[d * 32 + cq];
    float4 wm = Wm4[d * 32 + cq];
    #pragma unroll
    for (int i = 0; i < 4; ++i) {
      float xv = xt[(rg * 4 + i) * OUTC + d];
      ad[i].x += xv * wd.x; ad[i].y += xv * wd.y;
      ad[i].z += xv * wd.z; ad[i].w += xv * wd.w;
      am[i].x += xv * wm.x; am[i].y += xv * wm.y;
      am[i].z += xv * wm.z; am[i].w += xv * wm.w;
    }
  }
  float4 bm4 = ((const float4*)bm)[cq];
  float4 g4  = ((const float4*)gamma)[cq];
  float4 b4  = ((const float4*)beta)[cq];
  float4 m4  = ((const float4*)rmean)[cq];
  float4 v4  = ((const float4*)rvar)[cq];
  float4 sc;
  sc.x = g4.x * rsqrtf(v4.x + BN_EPS);
  sc.y = g4.y * rsqrtf(v4.y + BN_EPS);
  sc.z = g4.z * rsqrtf(v4.z + BN_EPS);
  sc.w = g4.w * rsqrtf(v4.w + BN_EPS);
  #pragma unroll
  for (int i = 0; i < 4; ++i) {
    int r = r0 + rg * 4 + i;
    ((float4*)(adst + (size_t)r * OUTC))[cq] = ad[i];
    float4 h;
    h.x = (am[i].x + bm4.x - m4.x) * sc.x + b4.x;
    h.y = (am[i].y + bm4.y - m4.y) * sc.y + b4.y;
    h.z = (am[i].z + bm4.z - m4.z) * sc.z + b4.z;
    h.w = (am[i].w + bm4.w - m4.w) * sc.w + b4.w;
    float4 o;
    o.x = silu_f(h.x); o.y = silu_f(h.y); o.z = silu_f(h.z); o.w = silu_f(h.w);
    ((float4*)(out + (size_t)r * OUTC))[cq] = o;
  }
}

// -------- branchless LEX sorted insert: key (d2, idx), ascending -------------
// Order-independent: final list = top-L by lex key regardless of stream order.
// Lex == stable-lo-index tie resolution (indices distinct).
template <int L>
__device__ __forceinline__ void ins_lex(float (&ds)[L], int (&is)[L],
                                        float d2, int j) {
  bool b[L];
  #pragma unroll
  for (int q = 0; q < L; ++q)
    b[q] = (d2 < ds[q]) || (d2 == ds[q] && j < is[q]);
  #pragma unroll
  for (int q = L - 1; q >= 1; --q) {
    ds[q] = b[q] ? (b[q - 1] ? ds[q - 1] : d2) : ds[q];
    is[q] = b[q] ? (b[q - 1] ? is[q - 1] : j) : is[q];
  }
  ds[0] = b[0] ? d2 : ds[0];
  is[0] = b[0] ? j : is[0];
}

__device__ __forceinline__ bool lex_lt(float d2, int j, float D, int J) {
  return (d2 < D) || (d2 == D && j < J);
}

// ---------------- K3: wave-per-target KNN, lane-parallel candidates ----------
// grid 8192 blocks x 256 thr: 4 targets/block (1 wave each).
// Lane scans 128 candidates (j = jj*64+lane, coalesced), keeps lex top-10.
// Two-level LDS merge (8x8) -> exact stable top-10; then verified tie logic.
__global__ __launch_bounds__(256) void k3_knn(
    const float* __restrict__ pos, const float4* __restrict__ ps4,
    int* __restrict__ knn_idx) {
  __shared__ float lmd[4][64][TOPL];   // 10 KB
  __shared__ int   lmi[4][64][TOPL];   // 10 KB
  __shared__ float pmd[4][8][TOPL];    // 1.25 KB
  __shared__ int   pmi[4][8][TOPL];    // 1.25 KB
  const int tid = threadIdx.x;
  const int w = tid >> 6;          // wave = target within block
  const int lane = tid & 63;
  const int i = blockIdx.x * 4 + w;
  const float pix = pos[i * 3 + 0];
  const float piy = pos[i * 3 + 1];
  const float piz = pos[i * 3 + 2];
  const float ni = __fadd_rn(__fadd_rn(__fmul_rn(pix, pix), __fmul_rn(piy, piy)),
                             __fmul_rn(piz, piz));
  float ds[TOPL]; int is[TOPL];
  #pragma unroll
  for (int q = 0; q < TOPL; ++q) { ds[q] = 3.0e38f; is[q] = 0; }
  #pragma unroll 2
  for (int jj = 0; jj < NSUB / 64; ++jj) {
    const int j = jj * 64 + lane;
    float4 q4 = ps4[j];
    float dot = __fmaf_rn(piz, q4.z, __fmaf_rn(piy, q4.y, __fmul_rn(pix, q4.x)));
    float d2 = __fadd_rn(__fsub_rn(ni, __fmul_rn(2.0f, dot)), q4.w);
    if (lex_lt(d2, j, ds[TOPL - 1], is[TOPL - 1])) ins_lex<TOPL>(ds, is, d2, j);
  }
  #pragma unroll
  for (int q = 0; q < TOPL; ++q) { lmd[w][lane][q] = ds[q]; lmi[w][lane][q] = is[q]; }
  __syncthreads();
  // level-1 merge: 32 threads, each merges 8 lane-lists -> 1 partial
  if (tid < 32) {
    const int mw = tid >> 3;
    const int g  = tid & 7;
    float fd[TOPL]; int fi[TOPL];
    #pragma unroll
    for (int q = 0; q < TOPL; ++q) { fd[q] = 3.0e38f; fi[q] = 0; }
    for (int src = 0; src < 8; ++src) {
      const int sl = g * 8 + src;
      #pragma unroll
      for (int q = 0; q < TOPL; ++q) {
        float d2 = lmd[mw][sl][q];
        int j = lmi[mw][sl][q];
        if (!lex_lt(d2, j, fd[TOPL - 1], fi[TOPL - 1])) break;  // sorted src
        ins_lex<TOPL>(fd, fi, d2, j);
      }
    }
    #pragma unroll
    for (int q = 0; q < TOPL; ++q) { pmd[mw][g][q] = fd[q]; pmi[mw][g][q] = fi[q]; }
  }
  __syncthreads();
  // level-2 merge: 4 threads, each merges 8 partials -> final; tie logic
  if (tid < 4) {
    const int mw = tid;
    const int ii = blockIdx.x * 4 + mw;
    float fd[TOPL]; int fi[TOPL];
    #pragma unroll
    for (int q = 0; q < TOPL; ++q) { fd[q] = 3.0e38f; fi[q] = 0; }
    for (int src = 0; src < 8; ++src) {
      #pragma unroll
      for (int q = 0; q < TOPL; ++q) {
        float d2 = pmd[mw][src][q];
        int j = pmi[mw][src][q];
        if (!lex_lt(d2, j, fd[TOPL - 1], fi[TOPL - 1])) break;
        ins_lex<TOPL>(fd, fi, d2, j);
      }
    }
    #pragma unroll
    for (int q = 0; q < KNN; ++q) knn_idx[ii * KNN + q] = fi[q];
    // exact tie (fd[7]==fd[8]) -> lower index already kept by lex order.
    // near-tie (0 < gap <= NT_TOL) -> fp64 truth rerank of the 8th slot.
    float gap8 = fd[KNN] - fd[KNN - 1];
    if (gap8 > 0.0f && gap8 <= NT_TOL) {
      const float tx = pos[ii * 3 + 0];
      const float ty = pos[ii * 3 + 1];
      const float tz = pos[ii * 3 + 2];
      const double px = (double)tx, py = (double)ty, pz = (double)tz;
      int cand[3];
      int nc = 2;
      cand[0] = fi[KNN - 1];
      cand[1] = fi[KNN];
      if (fd[KNN + 1] - fd[KNN - 1] <= NT_TOL) { cand[2] = fi[KNN + 1]; nc = 3; }
      int best = -1;
      double bd = 1.0e300;
      for (int q = 0; q < nc; ++q) {
        float4 q4 = ps4[cand[q]];
        double ddx = px - (double)q4.x;
        double ddy = py - (double)q4.y;
        double ddz = pz - (double)q4.z;
        double dd = ddx * ddx + ddy * ddy + ddz * ddz;
        bool better = (dd < bd) || (dd == bd && cand[q] < best);
        if (better) { bd = dd; best = cand[q]; }
      }
      knn_idx[ii * KNN + (KNN - 1)] = best;
    }
  }
}

// ---------------- K4: message passing + softmax + scatter-add ----------------
__global__ __launch_bounds__(256) void k4_message(
    const float* __restrict__ pos, const float* __restrict__ pos_sub,
    const int* __restrict__ knn_idx, const float* __restrict__ adst,
    const float* __restrict__ asrc, const float* __restrict__ vlin,
    const float* __restrict__ Wp, const float* __restrict__ bp,
    const float* __restrict__ Wa, const float* __restrict__ ba,
    float* __restrict__ out) {
  __shared__ __align__(16) float wa[OUTC * OUTC];
  __shared__ __align__(16) float e_s[KNN][OUTC];
  __shared__ __align__(16) float vpd_s[KNN][OUTC];
  __shared__ __align__(16) float a_s[KNN][OUTC];
  __shared__ float wp_s[3][OUTC];
  __shared__ float bp_s[OUTC];
  __shared__ __align__(16) float ba_s[OUTC];
  const int tid = threadIdx.x;
  {
    const float4* src = (const float4*)Wa;
    float4* dst = (float4*)wa;
    #pragma unroll
    for (int i = 0; i < 16; ++i) dst[tid + 256 * i] = src[tid + 256 * i];
  }
  if (tid < OUTC) {
    wp_s[0][tid] = Wp[0 * OUTC + tid];
    wp_s[1][tid] = Wp[1 * OUTC + tid];
    wp_s[2][tid] = Wp[2 * OUTC + tid];
    bp_s[tid] = bp[tid];
    ba_s[tid] = ba[tid];
  }
  __syncthreads();
  const int k = tid >> 5;
  const int l = tid & 31;
  for (int it = 0; it < 16; ++it) {
    const int i = blockIdx.x * 16 + it;
    const int j = knn_idx[i * KNN + k];
    const float pix = pos[i * 3 + 0], piy = pos[i * 3 + 1], piz = pos[i * 3 + 2];
    const float dx = pix - pos_sub[j * 3 + 0];
    const float dy = piy - pos_sub[j * 3 + 1];
    const float dz = piz - pos_sub[j * 3 + 2];
    #pragma unroll
    for (int s = 0; s < 4; ++s) {
      const int d = l + 32 * s;
      float tpre = __fadd_rn(
          __fadd_rn(__fadd_rn(__fmul_rn(dx, wp_s[0][d]), __fmul_rn(dy, wp_s[1][d])),
                    __fmul_rn(dz, wp_s[2][d])),
          bp_s[d]);
      float delta = silu_f(tpre);
      e_s[k][d] = (adst[(size_t)i * OUTC + d] - asrc[(size_t)j * OUTC + d]) + delta;
      vpd_s[k][d] = vlin[(size_t)j * OUTC + d] + delta;
    }
    __syncthreads();
    {
      float4 acc = ((const float4*)ba_s)[l];
      const float4* wa4 = (const float4*)wa;
      #pragma unroll 4
      for (int d = 0; d < OUTC; ++d) {
        float eb = e_s[k][d];
        float4 w4 = wa4[d * 32 + l];
        acc.x += eb * w4.x; acc.y += eb * w4.y;
        acc.z += eb * w4.z; acc.w += eb * w4.w;
      }
      float4 av;
      av.x = silu_f(acc.x); av.y = silu_f(acc.y);
      av.z = silu_f(acc.z); av.w = silu_f(acc.w);
      ((float4*)&a_s[k][0])[l] = av;
    }
    __syncthreads();
    if (tid < OUTC) {
      const int c = tid;
      float av[KNN];
      #pragma unroll
      for (int kk = 0; kk < KNN; ++kk) av[kk] = a_s[kk][c];
      float m = av[0];
      #pragma unroll
      for (int kk = 1; kk < KNN; ++kk) m = fmaxf(m, av[kk]);
      float w[KNN]; float denom = 0.f;
      #pragma unroll
      for (int kk = 0; kk < KNN; ++kk) { w[kk] = __expf(av[kk] - m); denom += w[kk]; }
      const float inv = 1.0f / denom;
      float o = 0.f;
      #pragma unroll
      for (int kk = 0; kk < KNN; ++kk) o += (w[kk] * inv) * vpd_s[kk][c];
      out[(size_t)i * OUTC + c] += o;
    }
    __syncthreads();
  }
}

extern "C" void kernel_launch(void* const* d_in, const int* in_sizes, int n_in,
                              void* d_out, int out_size, void* d_ws, size_t ws_size,
                              hipStream_t stream) {
  const float* x       = (const float*)d_in[0];
  const float* x_sub   = (const float*)d_in[1];
  const float* pos     = (const float*)d_in[2];
  const float* pos_sub = (const float*)d_in[3];
  const float* Wlin    = (const float*)d_in[4];
  const float* Wsrc    = (const float*)d_in[5];
  const float* Wdst    = (const float*)d_in[6];
  const float* Wp      = (const float*)d_in[7];
  const float* bp      = (const float*)d_in[8];
  const float* Wa      = (const float*)d_in[9];
  const float* ba      = (const float*)d_in[10];
  const float* Wm      = (const float*)d_in[11];
  const float* bm      = (const float*)d_in[12];
  const float* gamma   = (const float*)d_in[13];
  const float* beta    = (const float*)d_in[14];
  const float* rmean   = (const float*)d_in[15];
  const float* rvar    = (const float*)d_in[16];
  float* out = (float*)d_out;

  float* asrc = (float*)d_ws;
  float* vlin = asrc + (size_t)NSUB * OUTC;
  float* adst = vlin + (size_t)NSUB * OUTC;
  int* knn    = (int*)(adst + (size_t)NPTS * OUTC);
  float4* ps4 = (float4*)(knn + (size_t)NPTS * KNN);

  hipLaunchKernelGGL(k0_pack, dim3((NSUB + 255) / 256), dim3(256), 0, stream,
                     pos_sub, ps4);
  hipLaunchKernelGGL(k1_proj_sub, dim3(NSUB / 32), dim3(256), 0, stream,
                     x_sub, Wsrc, Wlin, asrc, vlin);
  hipLaunchKernelGGL(k2_proj_x, dim3(NPTS / 32), dim3(256), 0, stream,
                     x, Wdst, Wm, bm, gamma, beta, rmean, rvar, adst, out);
  hipLaunchKernelGGL(k3_knn, dim3(NPTS / 4), dim3(256), 0, stream,
                     pos, ps4, knn);
  hipLaunchKernelGGL(k4_message, dim3(NPTS / 16), dim3(256), 0, stream,
                     pos, pos_sub, knn, adst, asrc, vlin, Wp, bp, Wa, ba, out);
}

// Round 20
// 1584.481 us; speedup vs baseline: 7.9993x; 7.9993x over previous
//
#include <hip/hip_runtime.h>

#define NPTS 32768
#define NSUB 8192
#define INC 256
#define OUTC 128
#define KNN 8
#define TOPL 10
#define NT_TOL 1.0e-6f
#define BN_EPS 1e-5f

#define K3_STAGE 1024
#define K3_PASS (NSUB / K3_STAGE)

__device__ __forceinline__ float silu_f(float v) {
    return v / (1.0f + __expf(-v));
}

// ---------------- K0: pack pos_sub -> float4(x,y,z,|q|^2) in workspace -------
__global__ __launch_bounds__(256) void k0_pack(
    const float* __restrict__ pos_sub, float4* __restrict__ ps4) {
  int s = blockIdx.x * 256 + threadIdx.x;
  if (s < NSUB) {
    float qx = pos_sub[s * 3 + 0];
    float qy = pos_sub[s * 3 + 1];
    float qz = pos_sub[s * 3 + 2];
    float nrm = __fadd_rn(__fadd_rn(__fmul_rn(qx, qx), __fmul_rn(qy, qy)),
                          __fmul_rn(qz, qz));
    ps4[s] = make_float4(qx, qy, qz, nrm);
  }
}

// ---------------- K1: asrc = x_sub @ Wsrc, vlin = x_sub @ Wlin ----------------
__global__ __launch_bounds__(256) void k1_proj_sub(
    const float* __restrict__ x_sub, const float* __restrict__ Wsrc,
    const float* __restrict__ Wlin, float* __restrict__ asrc,
    float* __restrict__ vlin) {
  __shared__ __align__(16) float xs[32 * INC];
  const int tid = threadIdx.x;
  const int r0 = blockIdx.x * 32;
  {
    const float4* src = (const float4*)(x_sub + (size_t)r0 * INC);
    float4* dst = (float4*)xs;
    #pragma unroll
    for (int i = 0; i < 8; ++i) dst[tid + 256 * i] = src[tid + 256 * i];
  }
  __syncthreads();
  const int cq = tid & 31;
  const int rg = tid >> 5;
  float4 acc_s[4], acc_l[4];
  #pragma unroll
  for (int i = 0; i < 4; ++i) {
    acc_s[i] = make_float4(0.f, 0.f, 0.f, 0.f);
    acc_l[i] = make_float4(0.f, 0.f, 0.f, 0.f);
  }
  const float4* Ws4 = (const float4*)Wsrc;
  const float4* Wl4 = (const float4*)Wlin;
  #pragma unroll 2
  for (int d = 0; d < INC; ++d) {
    float4 ws = Ws4[d * 32 + cq];
    float4 wl = Wl4[d * 32 + cq];
    #pragma unroll
    for (int i = 0; i < 4; ++i) {
      float xv = xs[(rg * 4 + i) * INC + d];
      acc_s[i].x += xv * ws.x; acc_s[i].y += xv * ws.y;
      acc_s[i].z += xv * ws.z; acc_s[i].w += xv * ws.w;
      acc_l[i].x += xv * wl.x; acc_l[i].y += xv * wl.y;
      acc_l[i].z += xv * wl.z; acc_l[i].w += xv * wl.w;
    }
  }
  #pragma unroll
  for (int i = 0; i < 4; ++i) {
    int r = r0 + rg * 4 + i;
    ((float4*)(asrc + (size_t)r * OUTC))[cq] = acc_s[i];
    ((float4*)(vlin + (size_t)r * OUTC))[cq] = acc_l[i];
  }
}

// ---------------- K2: adst = x @ Wdst ; d_out = silu(BN(x @ Wm + bm)) --------
__global__ __launch_bounds__(256) void k2_proj_x(
    const float* __restrict__ x, const float* __restrict__ Wdst,
    const float* __restrict__ Wm, const float* __restrict__ bm,
    const float* __restrict__ gamma, const float* __restrict__ beta,
    const float* __restrict__ rmean, const float* __restrict__ rvar,
    float* __restrict__ adst, float* __restrict__ out) {
  __shared__ __align__(16) float xt[32 * OUTC];
  const int tid = threadIdx.x;
  const int r0 = blockIdx.x * 32;
  {
    const float4* src = (const float4*)(x + (size_t)r0 * OUTC);
    float4* dst = (float4*)xt;
    #pragma unroll
    for (int i = 0; i < 4; ++i) dst[tid + 256 * i] = src[tid + 256 * i];
  }
  __syncthreads();
  const int cq = tid & 31;
  const int rg = tid >> 5;
  float4 ad[4], am[4];
  #pragma unroll
  for (int i = 0; i < 4; ++i) {
    ad[i] = make_float4(0.f, 0.f, 0.f, 0.f);
    am[i] = make_float4(0.f, 0.f, 0.f, 0.f);
  }
  const float4* Wd4 = (const float4*)Wdst;
  const float4* Wm4 = (const float4*)Wm;
  #pragma unroll 2
  for (int d = 0; d < OUTC; ++d) {
    float4 wd = Wd4[d * 32 + cq];
    float4 wm = Wm4[d * 32 + cq];
    #pragma unroll
    for (int i = 0; i < 4; ++i) {
      float xv = xt[(rg * 4 + i) * OUTC + d];
      ad[i].x += xv * wd.x; ad[i].y += xv * wd.y;
      ad[i].z += xv * wd.z; ad[i].w += xv * wd.w;
      am[i].x += xv * wm.x; am[i].y += xv * wm.y;
      am[i].z += xv * wm.z; am[i].w += xv * wm.w;
    }
  }
  float4 bm4 = ((const float4*)bm)[cq];
  float4 g4  = ((const float4*)gamma)[cq];
  float4 b4  = ((const float4*)beta)[cq];
  float4 m4  = ((const float4*)rmean)[cq];
  float4 v4  = ((const float4*)rvar)[cq];
  float4 sc;
  sc.x = g4.x * rsqrtf(v4.x + BN_EPS);
  sc.y = g4.y * rsqrtf(v4.y + BN_EPS);
  sc.z = g4.z * rsqrtf(v4.z + BN_EPS);
  sc.w = g4.w * rsqrtf(v4.w + BN_EPS);
  #pragma unroll
  for (int i = 0; i < 4; ++i) {
    int r = r0 + rg * 4 + i;
    ((float4*)(adst + (size_t)r * OUTC))[cq] = ad[i];
    float4 h;
    h.x = (am[i].x + bm4.x - m4.x) * sc.x + b4.x;
    h.y = (am[i].y + bm4.y - m4.y) * sc.y + b4.y;
    h.z = (am[i].z + bm4.z - m4.z) * sc.z + b4.z;
    h.w = (am[i].w + bm4.w - m4.w) * sc.w + b4.w;
    float4 o;
    o.x = silu_f(h.x); o.y = silu_f(h.y); o.z = silu_f(h.z); o.w = silu_f(h.w);
    ((float4*)(out + (size_t)r * OUTC))[cq] = o;
  }
}

// ---------------- top-L stable insert (insert-after-equals: lo-index ties) ---
// For an ascending-j candidate stream this equals lex (d2, j) order.
template <int L>
__device__ __forceinline__ void top_insert(float (&dist)[L], int (&ind)[L],
                                           float d2, int j) {
  int cnt = 0;
  #pragma unroll
  for (int q = 0; q < L; ++q) cnt += (dist[q] <= d2) ? 1 : 0;
  #pragma unroll
  for (int q = L - 2; q >= 0; --q) {
    bool sh = dist[q] > d2;
    dist[q + 1] = sh ? dist[q] : dist[q + 1];
    ind[q + 1]  = sh ? ind[q]  : ind[q + 1];
  }
  #pragma unroll
  for (int q = 0; q < L; ++q) {
    if (q == cnt) { dist[q] = d2; ind[q] = j; }
  }
}

// ---------------- lex (d2, j) insert — order-independent, = stable-lo --------
__device__ __forceinline__ bool lex_lt(float d2, int j, float D, int J) {
  return (d2 < D) || (d2 == D && j < J);
}
template <int L>
__device__ __forceinline__ void lex_insert(float (&dist)[L], int (&ind)[L],
                                           float d2, int j) {
  int cnt = 0;
  #pragma unroll
  for (int q = 0; q < L; ++q) cnt += lex_lt(d2, j, dist[q], ind[q]) ? 0 : 1;
  #pragma unroll
  for (int q = L - 2; q >= 0; --q) {
    bool sh = lex_lt(d2, j, dist[q], ind[q]);
    dist[q + 1] = sh ? dist[q] : dist[q + 1];
    ind[q + 1]  = sh ? ind[q]  : ind[q + 1];
  }
  #pragma unroll
  for (int q = 0; q < L; ++q) {
    if (q == cnt) { dist[q] = d2; ind[q] = j; }
  }
}

// ---------------- K3: R17 structure + 8-pass 16KB staging (occupancy fix) ----
// grid 512 blocks x 256 thr: 64 targets x 4 chunk-threads.
// Per pass: stage 1024 sources (16 KB); thread (t,cg) scans its 256-quarter.
// Per-thread stream is ascending-j (pass-major) -> scan identical to R17.
// Merge is lex-(d2,j) (order-independent) -> exact stable-lo global top-10.
__global__ __launch_bounds__(256) void k3_knn(
    const float* __restrict__ pos, const float4* __restrict__ ps4,
    int* __restrict__ knn_idx) {
  __shared__ __align__(16) float4 ps[K3_STAGE];  // 16 KB
  __shared__ float md[4][64][TOPL];              // 10 KB
  __shared__ int   mi[4][64][TOPL];              // 10 KB
  const int tid = threadIdx.x;
  const int t  = tid & 63;
  const int cg = tid >> 6;
  const int i  = blockIdx.x * 64 + t;
  const float pix = pos[i * 3 + 0];
  const float piy = pos[i * 3 + 1];
  const float piz = pos[i * 3 + 2];
  const float ni = __fadd_rn(__fadd_rn(__fmul_rn(pix, pix), __fmul_rn(piy, piy)),
                             __fmul_rn(piz, piz));
  float dist[TOPL]; int ind[TOPL];
  #pragma unroll
  for (int q = 0; q < TOPL; ++q) { dist[q] = 3.0e38f; ind[q] = 0; }
  const int base = cg * (K3_STAGE / 4);
  for (int p = 0; p < K3_PASS; ++p) {
    #pragma unroll
    for (int u = 0; u < K3_STAGE / 256; ++u)
      ps[tid + 256 * u] = ps4[p * K3_STAGE + tid + 256 * u];
    __syncthreads();
    const int joff = p * K3_STAGE + base;
    for (int jj = 0; jj < K3_STAGE / 4; ++jj) {
      float4 q4 = ps[base + jj];
      float dot = __fmaf_rn(piz, q4.z, __fmaf_rn(piy, q4.y, __fmul_rn(pix, q4.x)));
      float d2 = __fadd_rn(__fsub_rn(ni, __fmul_rn(2.0f, dot)), q4.w);
      if (d2 < dist[TOPL - 1]) top_insert<TOPL>(dist, ind, d2, joff + jj);
    }
    __syncthreads();
  }
  #pragma unroll
  for (int q = 0; q < TOPL; ++q) { md[cg][t][q] = dist[q]; mi[cg][t][q] = ind[q]; }
  __syncthreads();
  if (tid < 64) {
    float fd[TOPL]; int fi[TOPL];
    #pragma unroll
    for (int q = 0; q < TOPL; ++q) { fd[q] = 3.0e38f; fi[q] = 0; }
    for (int c = 0; c < 4; ++c) {
      #pragma unroll
      for (int q = 0; q < TOPL; ++q) {
        float d2 = md[c][tid][q];
        int jj = mi[c][tid][q];
        if (lex_lt(d2, jj, fd[TOPL - 1], fi[TOPL - 1]))
          lex_insert<TOPL>(fd, fi, d2, jj);
      }
    }
    const int ii = blockIdx.x * 64 + tid;
    #pragma unroll
    for (int q = 0; q < KNN; ++q) knn_idx[ii * KNN + q] = fi[q];
    // exact tie: lex already kept the lower index.
    // near-tie (0 < gap <= NT_TOL): fp64 truth rerank of the 8th slot.
    float gap8 = fd[KNN] - fd[KNN - 1];
    if (gap8 > 0.0f && gap8 <= NT_TOL) {
      const double px = (double)pix, py = (double)piy, pz = (double)piz;
      int cand[3];
      int nc = 2;
      cand[0] = fi[KNN - 1];
      cand[1] = fi[KNN];
      if (fd[KNN + 1] - fd[KNN - 1] <= NT_TOL) { cand[2] = fi[KNN + 1]; nc = 3; }
      int best = -1;
      double bd = 1.0e300;
      for (int q = 0; q < nc; ++q) {
        float4 q4 = ps4[cand[q]];
        double ddx = px - (double)q4.x;
        double ddy = py - (double)q4.y;
        double ddz = pz - (double)q4.z;
        double dd = ddx * ddx + ddy * ddy + ddz * ddz;
        bool better = (dd < bd) || (dd == bd && cand[q] < best);
        if (better) { bd = dd; best = cand[q]; }
      }
      knn_idx[ii * KNN + (KNN - 1)] = best;
    }
  }
}

// ---------------- K4: message passing + softmax + scatter-add ----------------
__global__ __launch_bounds__(256) void k4_message(
    const float* __restrict__ pos, const float* __restrict__ pos_sub,
    const int* __restrict__ knn_idx, const float* __restrict__ adst,
    const float* __restrict__ asrc, const float* __restrict__ vlin,
    const float* __restrict__ Wp, const float* __restrict__ bp,
    const float* __restrict__ Wa, const float* __restrict__ ba,
    float* __restrict__ out) {
  __shared__ __align__(16) float wa[OUTC * OUTC];
  __shared__ __align__(16) float e_s[KNN][OUTC];
  __shared__ __align__(16) float vpd_s[KNN][OUTC];
  __shared__ __align__(16) float a_s[KNN][OUTC];
  __shared__ float wp_s[3][OUTC];
  __shared__ float bp_s[OUTC];
  __shared__ __align__(16) float ba_s[OUTC];
  const int tid = threadIdx.x;
  {
    const float4* src = (const float4*)Wa;
    float4* dst = (float4*)wa;
    #pragma unroll
    for (int i = 0; i < 16; ++i) dst[tid + 256 * i] = src[tid + 256 * i];
  }
  if (tid < OUTC) {
    wp_s[0][tid] = Wp[0 * OUTC + tid];
    wp_s[1][tid] = Wp[1 * OUTC + tid];
    wp_s[2][tid] = Wp[2 * OUTC + tid];
    bp_s[tid] = bp[tid];
    ba_s[tid] = ba[tid];
  }
  __syncthreads();
  const int k = tid >> 5;
  const int l = tid & 31;
  for (int it = 0; it < 16; ++it) {
    const int i = blockIdx.x * 16 + it;
    const int j = knn_idx[i * KNN + k];
    const float pix = pos[i * 3 + 0], piy = pos[i * 3 + 1], piz = pos[i * 3 + 2];
    const float dx = pix - pos_sub[j * 3 + 0];
    const float dy = piy - pos_sub[j * 3 + 1];
    const float dz = piz - pos_sub[j * 3 + 2];
    #pragma unroll
    for (int s = 0; s < 4; ++s) {
      const int d = l + 32 * s;
      float tpre = __fadd_rn(
          __fadd_rn(__fadd_rn(__fmul_rn(dx, wp_s[0][d]), __fmul_rn(dy, wp_s[1][d])),
                    __fmul_rn(dz, wp_s[2][d])),
          bp_s[d]);
      float delta = silu_f(tpre);
      e_s[k][d] = (adst[(size_t)i * OUTC + d] - asrc[(size_t)j * OUTC + d]) + delta;
      vpd_s[k][d] = vlin[(size_t)j * OUTC + d] + delta;
    }
    __syncthreads();
    {
      float4 acc = ((const float4*)ba_s)[l];
      const float4* wa4 = (const float4*)wa;
      #pragma unroll 4
      for (int d = 0; d < OUTC; ++d) {
        float eb = e_s[k][d];
        float4 w4 = wa4[d * 32 + l];
        acc.x += eb * w4.x; acc.y += eb * w4.y;
        acc.z += eb * w4.z; acc.w += eb * w4.w;
      }
      float4 av;
      av.x = silu_f(acc.x); av.y = silu_f(acc.y);
      av.z = silu_f(acc.z); av.w = silu_f(acc.w);
      ((float4*)&a_s[k][0])[l] = av;
    }
    __syncthreads();
    if (tid < OUTC) {
      const int c = tid;
      float av[KNN];
      #pragma unroll
      for (int kk = 0; kk < KNN; ++kk) av[kk] = a_s[kk][c];
      float m = av[0];
      #pragma unroll
      for (int kk = 1; kk < KNN; ++kk) m = fmaxf(m, av[kk]);
      float w[KNN]; float denom = 0.f;
      #pragma unroll
      for (int kk = 0; kk < KNN; ++kk) { w[kk] = __expf(av[kk] - m); denom += w[kk]; }
      const float inv = 1.0f / denom;
      float o = 0.f;
      #pragma unroll
      for (int kk = 0; kk < KNN; ++kk) o += (w[kk] * inv) * vpd_s[kk][c];
      out[(size_t)i * OUTC + c] += o;
    }
    __syncthreads();
  }
}

extern "C" void kernel_launch(void* const* d_in, const int* in_sizes, int n_in,
                              void* d_out, int out_size, void* d_ws, size_t ws_size,
                              hipStream_t stream) {
  const float* x       = (const float*)d_in[0];
  const float* x_sub   = (const float*)d_in[1];
  const float* pos     = (const float*)d_in[2];
  const float* pos_sub = (const float*)d_in[3];
  const float* Wlin    = (const float*)d_in[4];
  const float* Wsrc    = (const float*)d_in[5];
  const float* Wdst    = (const float*)d_in[6];
  const float* Wp      = (const float*)d_in[7];
  const float* bp      = (const float*)d_in[8];
  const float* Wa      = (const float*)d_in[9];
  const float* ba      = (const float*)d_in[10];
  const float* Wm      = (const float*)d_in[11];
  const float* bm      = (const float*)d_in[12];
  const float* gamma   = (const float*)d_in[13];
  const float* beta    = (const float*)d_in[14];
  const float* rmean   = (const float*)d_in[15];
  const float* rvar    = (const float*)d_in[16];
  float* out = (float*)d_out;

  float* asrc = (float*)d_ws;
  float* vlin = asrc + (size_t)NSUB * OUTC;
  float* adst = vlin + (size_t)NSUB * OUTC;
  int* knn    = (int*)(adst + (size_t)NPTS * OUTC);
  float4* ps4 = (float4*)(knn + (size_t)NPTS * KNN);

  hipLaunchKernelGGL(k0_pack, dim3((NSUB + 255) / 256), dim3(256), 0, stream,
                     pos_sub, ps4);
  hipLaunchKernelGGL(k1_proj_sub, dim3(NSUB / 32), dim3(256), 0, stream,
                     x_sub, Wsrc, Wlin, asrc, vlin);
  hipLaunchKernelGGL(k2_proj_x, dim3(NPTS / 32), dim3(256), 0, stream,
                     x, Wdst, Wm, bm, gamma, beta, rmean, rvar, adst, out);
  hipLaunchKernelGGL(k3_knn, dim3(NPTS / 64), dim3(256), 0, stream,
                     pos, ps4, knn);
  hipLaunchKernelGGL(k4_message, dim3(NPTS / 16), dim3(256), 0, stream,
                     pos, pos_sub, knn, adst, asrc, vlin, Wp, bp, Wa, ba, out);
}